// Round 4
// baseline (1011.157 us; speedup 1.0000x reference)
//
#include <hip/hip_runtime.h>
#include <cstdint>
#include <cstddef>

// Problem constants (fixed by the reference setup)
#define NPATHS   2048
#define PLEN     64
#define DDIM     512
#define NNODES   8192
#define NELEMS   (NPATHS * PLEN)   // 131072
#define BCAP     64                // bucket capacity per node; P(count>64) ~ 1e-40 (Poisson mean 8)

// ---------------- task queue ----------------
#define NT_SCAT  512               // 256 elements each
#define NT_GEMM  1024              // 64x64 tiles: (8192/64) rows x (512/64) cols, ROW-MAJOR order
#define NT_AGG   2048              // 4 nodes each, node order
#define NT_TOTAL (NT_SCAT + NT_GEMM + NT_AGG)   // 3584

#define SCAT_DONE_VAL  (NT_SCAT * 256)          // every scatter-task thread adds 1
#define ROW_DONE_VAL   (8 * 256)                // 8 tiles per 64-row block x 256 threads
#define SPIN_CAP       8000000                  // ~0.25s @ s_sleep(1); ~1000x worst healthy wait

// ---------------- workspace layout ----------------
// q      : NNODES*DDIM f32 = 16 MiB  @ 0
// counts : NNODES i32               (atomic cursors; == final counts)
// bucket : NNODES*BCAP i32 = 2 MiB
// ctrl   : [ticket, scat_done, row_done[128]]   (ws_size ~1 GiB per poison fills)
#define WS_Q_OFF      0
#define WS_COUNT_OFF  (NNODES * DDIM * 4)
#define WS_BUCKET_OFF (WS_COUNT_OFF + NNODES * 4)
#define WS_CTRL_OFF   (WS_BUCKET_OFF + NNODES * BCAP * 4)
#define CTRL_WORDS    (2 + 128)

// ---------------------------------------------------------------------------
__global__ __launch_bounds__(256) void k_zero(int* __restrict__ counts,
                                              int* __restrict__ ctrl) {
    int i = blockIdx.x * 256 + threadIdx.x;
    if (i < NNODES) counts[i] = 0;
    if (i < CTRL_WORDS) ctrl[i] = 0;
}

// ---------------------------------------------------------------------------
// Single fused task-queue kernel. Deadlock-free by construction: tickets are
// taken in order by RUNNING blocks (grid of 1536 blocks is fully co-resident
// at >=4 blocks/CU anyway), so any block holding an agg ticket can only be
// waiting on producer tickets already held by resident, non-blocking blocks.
// Spins are BOUNDED (cap -> proceed) so a sync bug yields a wrong answer, not
// a hang. Only thread 0 polls (agent-scope atomic load); the rest of the
// block parks at __syncthreads(). GEMM tiles drain in row-major ticket order
// so q row-blocks become ready progressively and the HBM-bound agg phase
// overlaps the VALU-bound GEMM tail.
__global__ __launch_bounds__(256) void k_fused(const float* __restrict__ A,
                                               const float* __restrict__ B,
                                               const float* __restrict__ bias,
                                               float* __restrict__ q,
                                               const float* __restrict__ enc,
                                               const int* __restrict__ mask,
                                               const int* __restrict__ idx,
                                               int* __restrict__ counts,
                                               int* __restrict__ bucket,
                                               int* __restrict__ ctrl,
                                               float* __restrict__ out) {
    __shared__ float As[32][68];
    __shared__ float Bs[32][68];
    __shared__ int s_ticket;
    const int tid = threadIdx.x;

    int* ticket    = ctrl + 0;
    int* scat_done = ctrl + 1;
    int* row_done  = ctrl + 2;

    for (;;) {
        __syncthreads();                       // protect s_ticket + LDS reuse
        if (tid == 0) s_ticket = atomicAdd(ticket, 1);
        __syncthreads();
        const int t = s_ticket;
        if (t >= NT_TOTAL) return;             // uniform exit

        if (t < NT_SCAT) {
            // ---------------- scatter task ----------------
            int e = t * 256 + tid;
            if (mask[e] != 0) {
                int n = idx[e];
                int slot = atomicAdd(&counts[n], 1);
                if (slot < BCAP) bucket[(n << 6) + slot] = e;
            }
            __threadfence();                   // release own stores
            atomicAdd(scat_done, 1);           // wave-coalesced
        } else if (t < NT_SCAT + NT_GEMM) {
            // ---------------- GEMM task: one 64x64 tile ----------------
            const int g  = t - NT_SCAT;
            const int by = g >> 3;             // row-major: low rows finish first
            const int bx = g & 7;
            const int m0 = by * 64;
            const int n0 = bx * 64;
            const int tx = tid & 15;
            const int ty = tid >> 4;

            float acc[4][4] = {};

            const int a_m  = tid >> 3;         // 0..31 (+32)
            const int a_kq = tid & 7;          // float4 index along k
            const int b_k  = tid >> 4;         // 0..15 (+16)
            const int b_n4 = tid & 15;         // float4 index along n

            for (int k0 = 0; k0 < DDIM; k0 += 32) {
#pragma unroll
                for (int i = 0; i < 2; i++) {
                    int m = a_m + i * 32;
                    float4 v = *(const float4*)&A[(size_t)(m0 + m) * DDIM + k0 + 4 * a_kq];
                    As[4 * a_kq + 0][m] = v.x;
                    As[4 * a_kq + 1][m] = v.y;
                    As[4 * a_kq + 2][m] = v.z;
                    As[4 * a_kq + 3][m] = v.w;
                }
#pragma unroll
                for (int i = 0; i < 2; i++) {
                    int kk = b_k + i * 16;
                    *(float4*)&Bs[kk][4 * b_n4] =
                        *(const float4*)&B[(size_t)(k0 + kk) * DDIM + n0 + 4 * b_n4];
                }
                __syncthreads();

#pragma unroll
                for (int k = 0; k < 32; k++) {
                    float4 a = *(const float4*)&As[k][4 * ty];
                    float4 b = *(const float4*)&Bs[k][4 * tx];
                    float av[4] = {a.x, a.y, a.z, a.w};
                    float bv[4] = {b.x, b.y, b.z, b.w};
#pragma unroll
                    for (int i = 0; i < 4; i++)
#pragma unroll
                        for (int j = 0; j < 4; j++)
                            acc[i][j] = fmaf(av[i], bv[j], acc[i][j]);
                }
                __syncthreads();
            }

            float4 bv = *(const float4*)&bias[n0 + 4 * tx];
#pragma unroll
            for (int i = 0; i < 4; i++) {
                int m = m0 + 4 * ty + i;
                float4 c = make_float4(acc[i][0] + bv.x, acc[i][1] + bv.y,
                                       acc[i][2] + bv.z, acc[i][3] + bv.w);
                *(float4*)&q[(size_t)m * DDIM + n0 + 4 * tx] = c;
            }
            __threadfence();                   // release q-tile stores
            atomicAdd(&row_done[by], 1);       // wave-coalesced
        } else {
            // ---------------- agg task: 4 nodes (one wave each) ----------------
            const int a  = t - NT_SCAT - NT_GEMM;
            const int node = a * 4 + (tid >> 6);
            const int lane = tid & 63;
            const int rb = a >> 4;             // = node>>6, same for all 4 waves

            // thread 0 polls producers (bounded); block parks at barrier
            if (tid == 0) {
                int it = 0;
                while (__hip_atomic_load(scat_done, __ATOMIC_RELAXED,
                                         __HIP_MEMORY_SCOPE_AGENT) < SCAT_DONE_VAL
                       && it < SPIN_CAP) { __builtin_amdgcn_s_sleep(1); ++it; }
                it = 0;
                while (__hip_atomic_load(&row_done[rb], __ATOMIC_RELAXED,
                                         __HIP_MEMORY_SCOPE_AGENT) < ROW_DONE_VAL
                       && it < SPIN_CAP) { __builtin_amdgcn_s_sleep(1); ++it; }
            }
            __syncthreads();
            __threadfence();                   // acquire producer stores

            const float4* qr = (const float4*)(q + (size_t)node * DDIM);
            float4 q0 = qr[lane];
            float4 q1 = qr[64 + lane];

            int cnt = counts[node];
            cnt = cnt > BCAP ? BCAP : cnt;
            const int* br = bucket + ((size_t)node << 6);

            float m = -3.0e38f;   // finite neg-inf: avoids inf-inf NaNs
            float l = 0.0f;
            float4 a0 = make_float4(0.f, 0.f, 0.f, 0.f);
            float4 a1 = make_float4(0.f, 0.f, 0.f, 0.f);

            int j = 0;
            for (; j + 2 <= cnt; j += 2) {
                int e0 = br[j];
                int e1 = br[j + 1];
                const float4* r0 = (const float4*)(enc + (size_t)e0 * DDIM);
                const float4* r1 = (const float4*)(enc + (size_t)e1 * DDIM);
                float4 u0 = r0[lane], u1 = r0[64 + lane];
                float4 w0 = r1[lane], w1 = r1[64 + lane];

                float p0 = u0.x * q0.x + u0.y * q0.y + u0.z * q0.z + u0.w * q0.w
                         + u1.x * q1.x + u1.y * q1.y + u1.z * q1.z + u1.w * q1.w;
                float p1 = w0.x * q0.x + w0.y * q0.y + w0.z * q0.z + w0.w * q0.w
                         + w1.x * q1.x + w1.y * q1.y + w1.z * q1.z + w1.w * q1.w;
#pragma unroll
                for (int o = 1; o < 64; o <<= 1) {
                    p0 += __shfl_xor(p0, o, 64);
                    p1 += __shfl_xor(p1, o, 64);
                }

                float mn = fmaxf(m, fmaxf(p0, p1));
                float sc = __expf(m - mn);
                float g0 = __expf(p0 - mn);
                float g1 = __expf(p1 - mn);
                l = l * sc + g0 + g1;
                a0.x = a0.x * sc + g0 * u0.x + g1 * w0.x;
                a0.y = a0.y * sc + g0 * u0.y + g1 * w0.y;
                a0.z = a0.z * sc + g0 * u0.z + g1 * w0.z;
                a0.w = a0.w * sc + g0 * u0.w + g1 * w0.w;
                a1.x = a1.x * sc + g0 * u1.x + g1 * w1.x;
                a1.y = a1.y * sc + g0 * u1.y + g1 * w1.y;
                a1.z = a1.z * sc + g0 * u1.z + g1 * w1.z;
                a1.w = a1.w * sc + g0 * u1.w + g1 * w1.w;
                m = mn;
            }
            if (j < cnt) {
                int e = br[j];
                const float4* r0 = (const float4*)(enc + (size_t)e * DDIM);
                float4 u0 = r0[lane], u1 = r0[64 + lane];
                float p = u0.x * q0.x + u0.y * q0.y + u0.z * q0.z + u0.w * q0.w
                        + u1.x * q1.x + u1.y * q1.y + u1.z * q1.z + u1.w * q1.w;
#pragma unroll
                for (int o = 1; o < 64; o <<= 1) p += __shfl_xor(p, o, 64);
                float mn = fmaxf(m, p);
                float sc = __expf(m - mn);
                float g  = __expf(p - mn);
                l = l * sc + g;
                a0.x = a0.x * sc + g * u0.x;
                a0.y = a0.y * sc + g * u0.y;
                a0.z = a0.z * sc + g * u0.z;
                a0.w = a0.w * sc + g * u0.w;
                a1.x = a1.x * sc + g * u1.x;
                a1.y = a1.y * sc + g * u1.y;
                a1.z = a1.z * sc + g * u1.z;
                a1.w = a1.w * sc + g * u1.w;
            }

            float inv = 1.0f / fmaxf(l, 1e-12f);
            float4 o0 = make_float4(a0.x * inv, a0.y * inv, a0.z * inv, a0.w * inv);
            float4 o1 = make_float4(a1.x * inv, a1.y * inv, a1.z * inv, a1.w * inv);
            float4* orow = (float4*)(out + (size_t)node * DDIM);
            orow[lane]      = o0;
            orow[64 + lane] = o1;
        }
    }
}

// ---------------------------------------------------------------------------
extern "C" void kernel_launch(void* const* d_in, const int* in_sizes, int n_in,
                              void* d_out, int out_size, void* d_ws, size_t ws_size,
                              hipStream_t stream) {
    const float* enc  = (const float*)d_in[0];  // [2048,64,512] f32
    const int*   mask = (const int*)d_in[1];    // [2048,64] int32
    const int*   idx  = (const int*)d_in[2];    // [2048,64] int32
    const float* prev = (const float*)d_in[3];  // [8192,512] f32
    const float* Wq   = (const float*)d_in[5];  // [512,512] f32
    const float* bq   = (const float*)d_in[6];  // [512] f32
    float* out = (float*)d_out;

    char* ws      = (char*)d_ws;
    float* q      = (float*)(ws + WS_Q_OFF);
    int*   counts = (int*)(ws + WS_COUNT_OFF);
    int*   bucket = (int*)(ws + WS_BUCKET_OFF);
    int*   ctrl   = (int*)(ws + WS_CTRL_OFF);

    hipLaunchKernelGGL(k_zero, dim3(NNODES / 256), dim3(256), 0, stream, counts, ctrl);
    hipLaunchKernelGGL(k_fused, dim3(1536), dim3(256), 0, stream,
                       prev, Wq, bq, q, enc, mask, idx, counts, bucket, ctrl, out);
}